// Round 1
// baseline (196.851 us; speedup 1.0000x reference)
//
#include <hip/hip_runtime.h>
#include <math.h>

// HumanPoseModule: per-element rotation pipeline.
// glb_reduced_6d: (BT, 10, 6) f32 ; orientation_6d: (BT, 6, 6) f32
// out: (BT, 24, 3) f32
//
// REDUCED_IDX  = [1,2,3,6,9,12,13,14,16,17] -> R0..R9
// SENSOR_IDX   = [0,4,5,15,18,19]           -> O0..O5 (O0 = root)
// IGNORED_IDX  = [7,8,10,11,20,21,22,23]    -> output exactly 0
//
// full[j] = root @ X_j ; local[j] = full[parent(j)]^T @ full[j] ; out = axis-angle(local)
// Chain processed in dependency order so at most ~4 matrices are live.

__device__ __forceinline__ void rot6d(const float* __restrict__ d, float M[3][3]) {
    float a1x = d[0], a1y = d[1], a1z = d[2];
    float a2x = d[3], a2y = d[4], a2z = d[5];
    float n1 = sqrtf(a1x * a1x + a1y * a1y + a1z * a1z);
    float b1x = a1x / n1, b1y = a1y / n1, b1z = a1z / n1;
    float dt = b1x * a2x + b1y * a2y + b1z * a2z;
    float c2x = a2x - dt * b1x, c2y = a2y - dt * b1y, c2z = a2z - dt * b1z;
    float n2 = sqrtf(c2x * c2x + c2y * c2y + c2z * c2z);
    float b2x = c2x / n2, b2y = c2y / n2, b2z = c2z / n2;
    float b3x = b1y * b2z - b1z * b2y;
    float b3y = b1z * b2x - b1x * b2z;
    float b3z = b1x * b2y - b1y * b2x;
    M[0][0] = b1x; M[0][1] = b1y; M[0][2] = b1z;
    M[1][0] = b2x; M[1][1] = b2y; M[1][2] = b2z;
    M[2][0] = b3x; M[2][1] = b3y; M[2][2] = b3z;
}

// C = A @ B
__device__ __forceinline__ void matmul(const float A[3][3], const float B[3][3], float C[3][3]) {
#pragma unroll
    for (int i = 0; i < 3; ++i)
#pragma unroll
        for (int j = 0; j < 3; ++j)
            C[i][j] = A[i][0] * B[0][j] + A[i][1] * B[1][j] + A[i][2] * B[2][j];
}

// C = A^T @ B   (einsum 'jki,jkl->jil')
__device__ __forceinline__ void matTmul(const float A[3][3], const float B[3][3], float C[3][3]) {
#pragma unroll
    for (int i = 0; i < 3; ++i)
#pragma unroll
        for (int j = 0; j < 3; ++j)
            C[i][j] = A[0][i] * B[0][j] + A[1][i] * B[1][j] + A[2][i] * B[2][j];
}

__device__ __forceinline__ void mat2aa(const float m[3][3], float* __restrict__ out) {
    float m00 = m[0][0], m01 = m[0][1], m02 = m[0][2];
    float m10 = m[1][0], m11 = m[1][1], m12 = m[1][2];
    float m20 = m[2][0], m21 = m[2][1], m22 = m[2][2];
    float q0 = sqrtf(fmaxf(1.f + m00 + m11 + m22, 0.f));
    float q1 = sqrtf(fmaxf(1.f + m00 - m11 - m22, 0.f));
    float q2 = sqrtf(fmaxf(1.f - m00 + m11 - m22, 0.f));
    float q3 = sqrtf(fmaxf(1.f - m00 - m11 + m22, 0.f));
    // first-max argmax (matches jnp.argmax tie-breaking)
    int idx = 0;
    float best = q0;
    if (q1 > best) { best = q1; idx = 1; }
    if (q2 > best) { best = q2; idx = 2; }
    if (q3 > best) { best = q3; idx = 3; }
    float s1 = m21 - m12, s2 = m02 - m20, s3 = m10 - m01;
    float p1 = m10 + m01, p2 = m02 + m20, p3 = m12 + m21;
    float w = (idx == 0) ? q0 * q0 : (idx == 1) ? s1 : (idx == 2) ? s2 : s3;
    float x = (idx == 0) ? s1 : (idx == 1) ? q1 * q1 : (idx == 2) ? p1 : p2;
    float y = (idx == 0) ? s2 : (idx == 1) ? p1 : (idx == 2) ? q2 * q2 : p3;
    float z = (idx == 0) ? s3 : (idx == 1) ? p2 : (idx == 2) ? p3 : q3 * q3;
    float dnm = 2.f * fmaxf(best, 0.1f);
    w /= dnm; x /= dnm; y /= dnm; z /= dnm;
    float n = sqrtf(x * x + y * y + z * z);
    float half = atan2f(n, w);
    float angle = 2.f * half;
    bool small = fabsf(angle) < 1e-6f;
    float safe = small ? 1.f : angle;
    float sh = small ? (0.5f - angle * angle * (1.f / 48.f)) : (sinf(half) / safe);
    out[0] = x / sh;
    out[1] = y / sh;
    out[2] = z / sh;
}

__global__ __launch_bounds__(256) void pose_kernel(const float* __restrict__ glb,
                                                   const float* __restrict__ ori,
                                                   float* __restrict__ out, int BT) {
    int e = blockIdx.x * blockDim.x + threadIdx.x;
    if (e >= BT) return;

    // ---- load inputs (16B-aligned per element: 60 floats / 36 floats) ----
    float g[60];
    {
        const float4* gp = (const float4*)(glb + (size_t)e * 60);
#pragma unroll
        for (int i = 0; i < 15; ++i) {
            float4 v = gp[i];
            g[4 * i + 0] = v.x; g[4 * i + 1] = v.y; g[4 * i + 2] = v.z; g[4 * i + 3] = v.w;
        }
    }
    float o[36];
    {
        const float4* op = (const float4*)(ori + (size_t)e * 36);
#pragma unroll
        for (int i = 0; i < 9; ++i) {
            float4 v = op[i];
            o[4 * i + 0] = v.x; o[4 * i + 1] = v.y; o[4 * i + 2] = v.z; o[4 * i + 3] = v.w;
        }
    }

    float aa[72];
    // ignored joints -> exact zeros (axis-angle of identity)
#pragma unroll
    for (int j3 = 0; j3 < 3; ++j3) {
        aa[7 * 3 + j3] = 0.f;  aa[8 * 3 + j3] = 0.f;
        aa[10 * 3 + j3] = 0.f; aa[11 * 3 + j3] = 0.f;
        aa[20 * 3 + j3] = 0.f; aa[21 * 3 + j3] = 0.f;
        aa[22 * 3 + j3] = 0.f; aa[23 * 3 + j3] = 0.f;
    }

    float root[3][3];
    rot6d(o + 0, root);
    mat2aa(root, aa + 0);  // joint 0

    float T[3][3], Fa[3][3], Fb[3][3], Fc[3][3], L[3][3];

#define FULL_R(k, DST) { rot6d(g + (k) * 6, T); matmul(root, T, DST); }
#define FULL_O(s, DST) { rot6d(o + (s) * 6, T); matmul(root, T, DST); }
#define LOCAL_OUT(P, C, joint) { matTmul(P, C, L); mat2aa(L, aa + (joint) * 3); }

    // arm: 1 -> 4
    FULL_R(0, Fa);               // F1
    LOCAL_OUT(root, Fa, 1);
    FULL_O(1, Fb);               // F4
    LOCAL_OUT(Fa, Fb, 4);
    // arm: 2 -> 5
    FULL_R(1, Fa);               // F2
    LOCAL_OUT(root, Fa, 2);
    FULL_O(2, Fb);               // F5
    LOCAL_OUT(Fa, Fb, 5);
    // spine: 3 -> 6 -> 9
    FULL_R(2, Fa);               // F3
    LOCAL_OUT(root, Fa, 3);
    FULL_R(3, Fb);               // F6
    LOCAL_OUT(Fa, Fb, 6);
    FULL_R(4, Fa);               // F9
    LOCAL_OUT(Fb, Fa, 9);
    // from F9 (Fa): 12 -> 15
    FULL_R(5, Fb);               // F12
    LOCAL_OUT(Fa, Fb, 12);
    FULL_O(3, Fc);               // F15
    LOCAL_OUT(Fb, Fc, 15);
    // from F9: 13 -> 16 -> 18
    FULL_R(6, Fb);               // F13
    LOCAL_OUT(Fa, Fb, 13);
    FULL_R(8, Fc);               // F16
    LOCAL_OUT(Fb, Fc, 16);
    FULL_O(4, Fb);               // F18
    LOCAL_OUT(Fc, Fb, 18);
    // from F9: 14 -> 17 -> 19
    FULL_R(7, Fb);               // F14
    LOCAL_OUT(Fa, Fb, 14);
    FULL_R(9, Fc);               // F17
    LOCAL_OUT(Fb, Fc, 17);
    FULL_O(5, Fb);               // F19
    LOCAL_OUT(Fc, Fb, 19);

#undef FULL_R
#undef FULL_O
#undef LOCAL_OUT

    // ---- store (18 x float4 per element, 16B-aligned) ----
    float4* outp = (float4*)(out + (size_t)e * 72);
#pragma unroll
    for (int i = 0; i < 18; ++i) {
        float4 v;
        v.x = aa[4 * i + 0]; v.y = aa[4 * i + 1]; v.z = aa[4 * i + 2]; v.w = aa[4 * i + 3];
        outp[i] = v;
    }
}

extern "C" void kernel_launch(void* const* d_in, const int* in_sizes, int n_in,
                              void* d_out, int out_size, void* d_ws, size_t ws_size,
                              hipStream_t stream) {
    const float* glb = (const float*)d_in[0];   // (BT,10,6) f32
    const float* ori = (const float*)d_in[1];   // (BT,6,6)  f32
    float* out = (float*)d_out;                 // (BT,24,3) f32
    int BT = in_sizes[0] / 60;
    int block = 256;
    int grid = (BT + block - 1) / block;
    pose_kernel<<<grid, block, 0, stream>>>(glb, ori, out, BT);
}